// Round 2
// baseline (2451.856 us; speedup 1.0000x reference)
//
#include <hip/hip_runtime.h>
#include <hip/hip_bf16.h>
#include <stdint.h>

// ---------- helpers ----------
typedef short bf16x8 __attribute__((ext_vector_type(8)));
typedef float f32x4 __attribute__((ext_vector_type(4)));

__device__ __forceinline__ float b2f(ushort u){ return __uint_as_float(((uint32_t)u)<<16); }
__device__ __forceinline__ ushort f2b(float f){
  uint32_t u = __float_as_uint(f);
  u += 0x7fffu + ((u>>16)&1u);
  return (ushort)(u>>16);
}
__device__ __forceinline__ float hswish(float x){ return x*fminf(fmaxf(x+3.f,0.f),6.f)*(1.f/6.f); }

// ---------- K0: zero scratch accumulators ----------
__global__ void zero_f32(float* __restrict__ p, int n){
  int i = blockIdx.x*256 + threadIdx.x;
  if (i < n) p[i] = 0.f;
}

// ---------- convert f32 -> bf16 ----------
__global__ void cvt_bf16(const float* __restrict__ in, ushort* __restrict__ out, int n){
  int i = blockIdx.x*256 + threadIdx.x;
  if (i < n) out[i] = f2b(in[i]);
}

// ---------- K1: transpose im_emd (B,C,N) f32 -> At[(b*N+n)][c] bf16 ----------
__global__ __launch_bounds__(256) void transpose_kernel(const float* __restrict__ im, ushort* __restrict__ At){
  __shared__ ushort t[64][65];
  const int b = blockIdx.z;
  const int c0 = blockIdx.y*64, n0 = blockIdx.x*64;
  const int tx = threadIdx.x & 63, ty = threadIdx.x >> 6; // ty 0..3
  #pragma unroll
  for (int i=0;i<16;++i){
    int c = ty + i*4;
    t[c][tx] = f2b(im[((size_t)(b*1024 + c0+c))*9216 + n0 + tx]);
  }
  __syncthreads();
  const int cx = threadIdx.x & 31, ny = threadIdx.x >> 5; // ny 0..7
  #pragma unroll
  for (int j=0;j<8;++j){
    int n = ny + j*8;
    uint32_t u = (uint32_t)t[cx*2][n] | ((uint32_t)t[cx*2+1][n] << 16);
    *(uint32_t*)&At[((size_t)(b*9216 + n0+n))*1024 + c0 + cx*2] = u;
  }
}

// ---------- GEMM: C[m][n] = sum_k A[m*K+k]*B[n*K+k]  (bf16 in/out, f32 acc, MFMA) ----------
__global__ __launch_bounds__(256) void gemm_bt(
    const ushort* __restrict__ A, const ushort* __restrict__ Bm,
    ushort* __restrict__ Cm, int M, int N, int K)
{
  __shared__ __align__(16) ushort As[128*64];
  __shared__ __align__(16) ushort Bs[128*64];
  const int tid = threadIdx.x;
  const int l = tid & 63;
  const int w = tid >> 6;
  const int wm = w >> 1, wn = w & 1;
  const size_t m0 = (size_t)blockIdx.x * 128;
  const size_t n0 = (size_t)blockIdx.y * 128;
  const int lr = l & 15, lk = l >> 4;

  f32x4 acc[4][4];
  #pragma unroll
  for (int i=0;i<4;++i)
    #pragma unroll
    for (int j=0;j<4;++j) acc[i][j] = (f32x4){0.f,0.f,0.f,0.f};

  for (int kt = 0; kt < K; kt += 64) {
    #pragma unroll
    for (int it=0; it<4; ++it) {
      int idx = it*256 + tid;
      int row = idx >> 3, c8 = idx & 7;
      *(uint4*)&As[row*64 + c8*8] = *(const uint4*)&A[(m0+row)*K + kt + c8*8];
      *(uint4*)&Bs[row*64 + c8*8] = *(const uint4*)&Bm[(n0+row)*K + kt + c8*8];
    }
    __syncthreads();
    #pragma unroll
    for (int kk=0; kk<64; kk+=32) {
      bf16x8 af[4], bfr[4];
      #pragma unroll
      for (int i=0;i<4;++i) af[i] = *(const bf16x8*)&As[(wm*64 + i*16 + lr)*64 + kk + lk*8];
      #pragma unroll
      for (int j=0;j<4;++j) bfr[j] = *(const bf16x8*)&Bs[(wn*64 + j*16 + lr)*64 + kk + lk*8];
      #pragma unroll
      for (int i=0;i<4;++i)
        #pragma unroll
        for (int j=0;j<4;++j)
          acc[i][j] = __builtin_amdgcn_mfma_f32_16x16x32_bf16(af[i], bfr[j], acc[i][j], 0, 0, 0);
    }
    __syncthreads();
  }
  #pragma unroll
  for (int i=0;i<4;++i)
    #pragma unroll
    for (int j=0;j<4;++j)
      #pragma unroll
      for (int r=0;r<4;++r) {
        size_t row = m0 + wm*64 + i*16 + lk*4 + r;
        size_t col = n0 + wn*64 + j*16 + lr;
        Cm[row*N + col] = f2b(acc[i][j][r]);
      }
}

// ---------- column stats (sum, sumsq) with atomics; blockDim = C/8 ----------
__global__ void col_stats_v(const ushort* __restrict__ X, float* __restrict__ sums,
                            float* __restrict__ sqs, int C, int rpb)
{
  const int tid = threadIdx.x;
  const size_t r0 = (size_t)blockIdx.x * rpb;
  float s[8] = {0,0,0,0,0,0,0,0};
  float q[8] = {0,0,0,0,0,0,0,0};
  const ushort* base = X + r0*(size_t)C + (size_t)tid*8;
  for (int r=0;r<rpb;++r){
    uint4 u = *(const uint4*)(base + (size_t)r*C);
    const ushort* ub = (const ushort*)&u;
    #pragma unroll
    for (int e=0;e<8;++e){ float v=b2f(ub[e]); s[e]+=v; q[e]+=v*v; }
  }
  #pragma unroll
  for (int e=0;e<8;++e){
    atomicAdd(&sums[tid*8+e], s[e]);
    atomicAdd(&sqs [tid*8+e], q[e]);
  }
}

// ---------- BN finalize: scale = g*rsqrt(var+eps), shift = b - mu*scale ----------
__global__ void bn_finalize(const float* __restrict__ sums, const float* __restrict__ sqs,
                            const float* __restrict__ g, const float* __restrict__ bb,
                            float* __restrict__ scale, float* __restrict__ shift, int C, float invn)
{
  int c = blockIdx.x*256 + threadIdx.x;
  if (c < C){
    float mu = sums[c]*invn;
    float var = sqs[c]*invn - mu*mu;
    float k = g[c] * rsqrtf(var + 1e-5f);
    scale[c] = k;
    shift[c] = bb[c] - mu*k;
  }
}

// ---------- BN + hardswish in place on y1 (73728 x 512 bf16) ----------
__global__ __launch_bounds__(256) void bn_hswish(ushort* __restrict__ y, const float* __restrict__ scale, const float* __restrict__ shift)
{
  __shared__ float sc[512], sh[512];
  for (int i=threadIdx.x;i<512;i+=256){ sc[i]=scale[i]; sh[i]=shift[i]; }
  __syncthreads();
  const size_t total = (size_t)73728*512/8;
  for (size_t idx = (size_t)blockIdx.x*256+threadIdx.x; idx < total; idx += (size_t)gridDim.x*256){
    uint4 u = *(uint4*)&y[idx*8];
    ushort* up = (ushort*)&u;
    int c0 = ((int)(idx & 63))*8;
    #pragma unroll
    for (int e=0;e<8;++e){
      float x = b2f(up[e])*sc[c0+e] + sh[c0+e];
      up[e] = f2b(hswish(x));
    }
    *(uint4*)&y[idx*8] = u;
  }
}

// ---------- q = text @ Wq^T (raw, f32) ----------
__global__ __launch_bounds__(256) void q_gemm(const float* __restrict__ text, const float* __restrict__ Wq, float* __restrict__ qraw)
{
  __shared__ __align__(16) float xr[512];
  const int t = blockIdx.x, tid = threadIdx.x;
  for (int i=tid;i<512;i+=256) xr[i] = text[t*512+i];
  __syncthreads();
  #pragma unroll
  for (int cj=0;cj<2;++cj){
    int c = cj*256+tid;
    const float4* wp = (const float4*)(Wq + (size_t)c*512);
    const float4* xp = (const float4*)xr;
    float a=0.f;
    for (int u=0;u<128;++u){
      float4 wv = wp[u], xv = xp[u];
      a += wv.x*xv.x + wv.y*xv.y + wv.z*xv.z + wv.w*xv.w;
    }
    qraw[t*512+c]=a;
  }
}

// ---------- q BN over 60 rows (one block, 512 threads) ----------
__global__ __launch_bounds__(512) void q_bn_kernel(const float* __restrict__ qraw, const float* __restrict__ g,
                                                   const float* __restrict__ bb, float* __restrict__ qbn)
{
  int c = threadIdx.x;
  float s=0.f,q=0.f;
  for (int t=0;t<60;++t){ float v = qraw[t*512+c]; s+=v; q+=v*v; }
  float mu=s*(1.f/60.f), var=q*(1.f/60.f)-mu*mu;
  float k = g[c]*rsqrtf(var+1e-5f);
  float sh = bb[c]-mu*k;
  for (int t=0;t<60;++t) qbn[t*512+c] = qraw[t*512+c]*k+sh;
}

// ---------- scores: S[b][h][t][n] = q.k*scale + bias ----------
__global__ __launch_bounds__(128) void scores_kernel(
    const float* __restrict__ qbn, const ushort* __restrict__ kv,
    const float* __restrict__ scale2, const float* __restrict__ shift2,
    const float* __restrict__ biases, float* __restrict__ S)
{
  __shared__ __align__(16) float qs[60*64];
  __shared__ float s2k[64], t2k[64];
  __shared__ float bias_l[10000];
  const int tid = threadIdx.x;
  const int nb = blockIdx.x * 128;
  const int h = blockIdx.y, b = blockIdx.z;
  #pragma unroll
  for (int i=0;i<30;++i){ int idx = i*128+tid; int t = idx>>6, d = idx&63; qs[idx] = qbn[t*512 + h*64 + d]; }
  if (tid < 64){ s2k[tid] = scale2[h*192+tid]; t2k[tid] = shift2[h*192+tid]; }
  for (int i=tid; i<10000; i+=128) bias_l[i] = biases[h*10000+i];
  __syncthreads();
  const int n = nb + tid;
  float kreg[64];
  {
    const ushort* kp = kv + ((size_t)(b*9216+n))*1536 + h*192;
    #pragma unroll
    for (int u=0;u<8;++u){
      uint4 kk4 = *(const uint4*)&kp[u*8];
      const ushort* kb = (const ushort*)&kk4;
      #pragma unroll
      for (int e=0;e<8;++e) kreg[u*8+e] = b2f(kb[e])*s2k[u*8+e] + t2k[u*8+e];
    }
  }
  const int py = n/96, px = n - py*96;
  float* Srow = S + ((size_t)((b*8+h)*60))*9216 + n;
  for (int t=0;t<60;++t){
    const float4* qp = (const float4*)&qs[t*64];
    float a = 0.f;
    #pragma unroll
    for (int u=0;u<16;++u){
      float4 qv = qp[u];
      a += qv.x*kreg[u*4] + qv.y*kreg[u*4+1] + qv.z*kreg[u*4+2] + qv.w*kreg[u*4+3];
    }
    int d = t - px; if (d < 0) d = -d;
    Srow[(size_t)t*9216] = a*0.125f + bias_l[100*py + d];
  }
}

// ---------- per-row softmax stats: max, 1/sum(exp) ----------
__global__ __launch_bounds__(256) void softmax_stats(const float* __restrict__ S, float* __restrict__ rmax_, float* __restrict__ rinv_)
{
  const int row = blockIdx.x, tid = threadIdx.x;
  const float4* p = (const float4*)(S + (size_t)row*9216);
  float4 vals[9];
  float m = -1e30f;
  #pragma unroll
  for (int i=0;i<9;++i){ float4 v = p[i*256+tid]; vals[i]=v; m = fmaxf(m, fmaxf(fmaxf(v.x,v.y),fmaxf(v.z,v.w))); }
  #pragma unroll
  for (int o=32;o>0;o>>=1) m = fmaxf(m, __shfl_xor(m, o));
  __shared__ float wm[4], ws[4];
  if ((tid&63)==0) wm[tid>>6]=m;
  __syncthreads();
  m = fmaxf(fmaxf(wm[0],wm[1]),fmaxf(wm[2],wm[3]));
  float ssum=0.f;
  #pragma unroll
  for (int i=0;i<9;++i){ float4 v=vals[i]; ssum += __expf(v.x-m)+__expf(v.y-m)+__expf(v.z-m)+__expf(v.w-m); }
  #pragma unroll
  for (int o=32;o>0;o>>=1) ssum += __shfl_xor(ssum,o);
  if ((tid&63)==0) ws[tid>>6]=ssum;
  __syncthreads();
  if (tid==0){ rmax_[row]=m; rinv_[row]=1.f/(ws[0]+ws[1]+ws[2]+ws[3]); }
}

// ---------- PV: attn_out[b][t][h*128+dv] += sum_n P*v  (split over 8 n-chunks, atomics) ----------
__global__ __launch_bounds__(256) void pv_kernel(
    const float* __restrict__ S, const ushort* __restrict__ kv,
    const float* __restrict__ scale2, const float* __restrict__ shift2,
    const float* __restrict__ rmax, const float* __restrict__ rinv,
    float* __restrict__ attn_out)
{
  __shared__ __align__(16) float P[60*64];
  __shared__ float rm[60], ri[60];
  const int tid = threadIdx.x;
  const int nc = blockIdx.x, h = blockIdx.y, b = blockIdx.z;
  const int dv = tid & 127, g = tid >> 7;
  const int bh = b*8+h;
  if (tid < 60){ rm[tid] = rmax[bh*60+tid]; ri[tid] = rinv[bh*60+tid]; }
  const float sv = scale2[h*192+64+dv], tv = shift2[h*192+64+dv];
  float acc[60];
  #pragma unroll
  for (int t=0;t<60;++t) acc[t]=0.f;
  __syncthreads();
  for (int cc=0; cc<18; ++cc){
    const int n0 = nc*1152 + cc*64;
    #pragma unroll
    for (int i=0;i<15;++i){
      int idx = i*256+tid; int t = idx>>6, nn = idx&63;
      float s = S[((size_t)(bh*60+t))*9216 + n0+nn];
      P[idx] = __expf(s - rm[t]) * ri[t];
    }
    __syncthreads();
    const ushort* vp = kv + ((size_t)(b*9216+n0+g*32))*1536 + h*192+64+dv;
    #pragma unroll
    for (int n4=0;n4<8;++n4){
      float v0 = b2f(vp[(n4*4+0)*1536])*sv+tv;
      float v1 = b2f(vp[(n4*4+1)*1536])*sv+tv;
      float v2 = b2f(vp[(n4*4+2)*1536])*sv+tv;
      float v3 = b2f(vp[(n4*4+3)*1536])*sv+tv;
      const int nn = g*32 + n4*4;
      #pragma unroll
      for (int t=0;t<60;++t){
        float4 p4 = *(const float4*)&P[t*64+nn];
        acc[t] += p4.x*v0 + p4.y*v1 + p4.z*v2 + p4.w*v3;
      }
    }
    __syncthreads();
  }
  float* op = attn_out + ((size_t)(b*60))*1024 + h*128 + dv;
  #pragma unroll
  for (int t=0;t<60;++t) atomicAdd(&op[(size_t)t*1024], acc[t]);
}

// ---------- small row GEMM: out[rb][c] = sum_i f(X[rb][i]) * W[c][i] ----------
// MODE 0: identity; 1: hardswish; 2: BN(scale,shift) then hardswish
template<int CIN, int COUT, int MODE>
__global__ __launch_bounds__(256) void rowgemm(
    const float* __restrict__ X, const float* __restrict__ Wt,
    const float* __restrict__ sc, const float* __restrict__ sh,
    float* __restrict__ out)
{
  __shared__ __align__(16) float xr[CIN];
  const int rb = blockIdx.x, tid = threadIdx.x;
  for (int i=tid; i<CIN; i+=256){
    float v = X[(size_t)rb*CIN + i];
    if constexpr (MODE==2) v = v*sc[i]+sh[i];
    if constexpr (MODE>=1) v = hswish(v);
    xr[i]=v;
  }
  __syncthreads();
  #pragma unroll
  for (int cj=0; cj<COUT/256; ++cj){
    int c = cj*256 + tid;
    const float4* wp = (const float4*)(Wt + (size_t)c*CIN);
    const float4* xp = (const float4*)xr;
    float a=0.f;
    for (int u=0;u<CIN/4;++u){
      float4 wv = wp[u], xv = xp[u];
      a += wv.x*xv.x + wv.y*xv.y + wv.z*xv.z + wv.w*xv.w;
    }
    out[(size_t)rb*COUT + c] = a;
  }
}

// ---------- stats over 480 rows + finalize (no atomics) ----------
template<int C>
__global__ void stats480(const float* __restrict__ X, const float* __restrict__ g,
                         const float* __restrict__ bb, float* __restrict__ sc, float* __restrict__ sh)
{
  int c = blockIdx.x*256 + threadIdx.x;
  float s=0.f, q=0.f;
  for (int r=0;r<480;++r){ float v = X[(size_t)r*C + c]; s+=v; q+=v*v; }
  float mu = s*(1.f/480.f), var = q*(1.f/480.f)-mu*mu;
  float k = g[c] * rsqrtf(var+1e-5f);
  sc[c]=k; sh[c]=bb[c] - mu*k;
}

// ---------- textd = text + BN(proj_raw) ----------
__global__ void make_textd(const float* __restrict__ praw, const float* __restrict__ sp, const float* __restrict__ tp,
                           const float* __restrict__ text, float* __restrict__ textd)
{
  int i = blockIdx.x*256+threadIdx.x;
  if (i < 480*512){
    int c = i & 511, rb = i >> 9, t = rb % 60;
    textd[i] = text[t*512+c] + praw[i]*sp[c]+tp[c];
  }
}

// ---------- final: out = BN(f2_raw) + textd, batch 0, f32 ----------
__global__ void final_out(const float* __restrict__ f2raw, const float* __restrict__ sf, const float* __restrict__ tf,
                          const float* __restrict__ textd, float* __restrict__ outp)
{
  int i = blockIdx.x*256+threadIdx.x;
  if (i < 60*512){ int c = i & 511; outp[i] = f2raw[i]*sf[c]+tf[c] + textd[i]; }
}

extern "C" void kernel_launch(void* const* d_in, const int* in_sizes, int n_in,
                              void* d_out, int out_size, void* d_ws, size_t ws_size,
                              hipStream_t stream)
{
  (void)in_sizes; (void)n_in; (void)out_size; (void)ws_size;
  const float* im    = (const float*)d_in[0];
  const float* text  = (const float*)d_in[1];
  const float* W_dc  = (const float*)d_in[2];
  const float* g_dc  = (const float*)d_in[3];
  const float* b_dc  = (const float*)d_in[4];
  const float* W_kv  = (const float*)d_in[5];
  const float* g_kv  = (const float*)d_in[6];
  const float* b_kv  = (const float*)d_in[7];
  const float* W_q   = (const float*)d_in[8];
  const float* g_q   = (const float*)d_in[9];
  const float* b_q   = (const float*)d_in[10];
  const float* W_proj= (const float*)d_in[11];
  const float* g_proj= (const float*)d_in[12];
  const float* b_proj= (const float*)d_in[13];
  const float* biases= (const float*)d_in[14];
  const float* W_f1  = (const float*)d_in[15];
  const float* g_f1  = (const float*)d_in[16];
  const float* b_f1  = (const float*)d_in[17];
  const float* W_f2  = (const float*)d_in[18];
  const float* g_f2  = (const float*)d_in[19];
  const float* b_f2  = (const float*)d_in[20];
  float* outp = (float*)d_out;

  char* p = (char*)d_ws;
  auto alloc = [&](size_t bytes)->char*{ char* r = p; p += (bytes+255)&~(size_t)255; return r; };
  // zero zone (contiguous)
  float* s1_sum = (float*)alloc(512*4);
  float* s1_sq  = (float*)alloc(512*4);
  float* s2_sum = (float*)alloc(1536*4);
  float* s2_sq  = (float*)alloc(1536*4);
  float* attn_o = (float*)alloc((size_t)480*1024*4);
  float* zero_base = s1_sum; const int zero_n = 495616;
  // rest
  float* sc1 = (float*)alloc(512*4);
  float* sh1 = (float*)alloc(512*4);
  float* sc2 = (float*)alloc(1536*4);
  float* sh2 = (float*)alloc(1536*4);
  float* qraw = (float*)alloc(60*512*4);
  float* qbn  = (float*)alloc(60*512*4);
  float* rmaxb = (float*)alloc(3840*4);
  float* rinvb = (float*)alloc(3840*4);
  float* proj_raw = (float*)alloc((size_t)480*512*4);
  float* sp=(float*)alloc(512*4); float* tp=(float*)alloc(512*4);
  float* textd=(float*)alloc((size_t)480*512*4);
  float* sf1=(float*)alloc(1024*4); float* tf1=(float*)alloc(1024*4);
  float* f1_raw=(float*)alloc((size_t)480*1024*4);
  float* sf2=(float*)alloc(512*4); float* tf2=(float*)alloc(512*4);
  float* f2_raw=(float*)alloc((size_t)480*512*4);
  ushort* Wdc_b = (ushort*)alloc((size_t)512*1024*2);
  ushort* Wkv_b = (ushort*)alloc((size_t)1536*512*2);
  ushort* y1 = (ushort*)alloc((size_t)73728*512*2);
  ushort* kv = (ushort*)alloc((size_t)73728*1536*2);
  ushort* At = (ushort*)alloc((size_t)73728*1024*2);
  float* S = (float*)At;  // alias: At dead after gemm1; S (135MB) fits in At (151MB)

  zero_f32<<<1936,256,0,stream>>>(zero_base, zero_n);
  cvt_bf16<<<2048,256,0,stream>>>(W_dc, Wdc_b, 512*1024);
  cvt_bf16<<<3072,256,0,stream>>>(W_kv, Wkv_b, 1536*512);
  transpose_kernel<<<dim3(144,16,8),256,0,stream>>>(im, At);
  gemm_bt<<<dim3(576,4),256,0,stream>>>(At, Wdc_b, y1, 73728, 512, 1024);
  col_stats_v<<<288,64,0,stream>>>(y1, s1_sum, s1_sq, 512, 256);
  bn_finalize<<<2,256,0,stream>>>(s1_sum, s1_sq, g_dc, b_dc, sc1, sh1, 512, 1.f/73728.f);
  bn_hswish<<<2048,256,0,stream>>>(y1, sc1, sh1);
  gemm_bt<<<dim3(576,12),256,0,stream>>>(y1, Wkv_b, kv, 73728, 1536, 512);
  col_stats_v<<<288,192,0,stream>>>(kv, s2_sum, s2_sq, 1536, 256);
  bn_finalize<<<6,256,0,stream>>>(s2_sum, s2_sq, g_kv, b_kv, sc2, sh2, 1536, 1.f/73728.f);
  q_gemm<<<60,256,0,stream>>>(text, W_q, qraw);
  q_bn_kernel<<<1,512,0,stream>>>(qraw, g_q, b_q, qbn);
  scores_kernel<<<dim3(72,8,8),128,0,stream>>>(qbn, kv, sc2, sh2, biases, S);
  softmax_stats<<<3840,256,0,stream>>>(S, rmaxb, rinvb);
  pv_kernel<<<dim3(8,8,8),256,0,stream>>>(S, kv, sc2, sh2, rmaxb, rinvb, attn_o);
  rowgemm<1024,512,1><<<480,256,0,stream>>>(attn_o, W_proj, nullptr, nullptr, proj_raw);
  stats480<512><<<2,256,0,stream>>>(proj_raw, g_proj, b_proj, sp, tp);
  make_textd<<<960,256,0,stream>>>(proj_raw, sp, tp, text, textd);
  rowgemm<512,1024,0><<<480,256,0,stream>>>(textd, W_f1, nullptr, nullptr, f1_raw);
  stats480<1024><<<4,256,0,stream>>>(f1_raw, g_f1, b_f1, sf1, tf1);
  rowgemm<1024,512,2><<<480,256,0,stream>>>(f1_raw, W_f2, sf1, tf1, f2_raw);
  stats480<512><<<2,256,0,stream>>>(f2_raw, g_f2, b_f2, sf2, tf2);
  final_out<<<120,256,0,stream>>>(f2_raw, sf2, tf2, textd, outp);
}

// Round 3
// 1491.829 us; speedup vs baseline: 1.6435x; 1.6435x over previous
//
#include <hip/hip_runtime.h>
#include <hip/hip_bf16.h>
#include <stdint.h>

typedef short bf16x8 __attribute__((ext_vector_type(8)));
typedef float f32x4 __attribute__((ext_vector_type(4)));

__device__ __forceinline__ float b2f(ushort u){ return __uint_as_float(((uint32_t)u)<<16); }
__device__ __forceinline__ ushort f2b(float f){
  uint32_t u = __float_as_uint(f);
  u += 0x7fffu + ((u>>16)&1u);
  return (ushort)(u>>16);
}
__device__ __forceinline__ float hswish(float x){ return x*fminf(fmaxf(x+3.f,0.f),6.f)*(1.f/6.f); }

// async global->LDS 16B (dest = wave-uniform base + lane*16)
__device__ __forceinline__ void gll16(const void* g, void* l){
  __builtin_amdgcn_global_load_lds((const __attribute__((address_space(1))) void*)g,
                                   (__attribute__((address_space(3))) void*)l, 16, 0, 0);
}

// ---------- zero scratch accumulators ----------
__global__ void zero_f32(float* __restrict__ p, int n){
  int i = blockIdx.x*256 + threadIdx.x;
  if (i < n) p[i] = 0.f;
}

// ---------- f32 -> bf16 ----------
__global__ void cvt_bf16(const float* __restrict__ in, ushort* __restrict__ out, int n){
  int i = blockIdx.x*256 + threadIdx.x;
  if (i < n) out[i] = f2b(in[i]);
}

// ---------- transpose im_emd (B,C,N) f32 -> At[(b*N+n)][c] bf16 ----------
__global__ __launch_bounds__(256) void transpose_kernel(const float* __restrict__ im, ushort* __restrict__ At){
  __shared__ ushort t[64][65];
  const int b = blockIdx.z;
  const int c0 = blockIdx.y*64, n0 = blockIdx.x*64;
  const int tx = threadIdx.x & 63, ty = threadIdx.x >> 6;
  #pragma unroll
  for (int i=0;i<16;++i){
    int c = ty + i*4;
    t[c][tx] = f2b(im[((size_t)(b*1024 + c0+c))*9216 + n0 + tx]);
  }
  __syncthreads();
  const int cx = threadIdx.x & 31, ny = threadIdx.x >> 5;
  #pragma unroll
  for (int j=0;j<8;++j){
    int n = ny + j*8;
    uint32_t u = (uint32_t)t[cx*2][n] | ((uint32_t)t[cx*2+1][n] << 16);
    *(uint32_t*)&At[((size_t)(b*9216 + n0+n))*1024 + c0 + cx*2] = u;
  }
}

// ---------- MFMA GEMM: C[m][n] = sum_k A[m*K+k]*B[n*K+k], bf16, async LDS staging ----------
__global__ __launch_bounds__(256) void gemm_bt(
    const ushort* __restrict__ A, const ushort* __restrict__ Bm,
    ushort* __restrict__ Cm, int M, int N, int K)
{
  __shared__ __align__(16) ushort As[128*64];
  __shared__ __align__(16) ushort Bs[128*64];
  const int tid = threadIdx.x;
  const int l = tid & 63;
  const int w = tid >> 6;
  const int wm = w >> 1, wn = w & 1;
  const size_t m0 = (size_t)blockIdx.x * 128;
  const size_t n0 = (size_t)blockIdx.y * 128;
  const int lr = l & 15, lk = l >> 4;
  const int wbase = tid & ~63;   // w*64, wave-uniform

  f32x4 acc[4][4];
  #pragma unroll
  for (int i=0;i<4;++i)
    #pragma unroll
    for (int j=0;j<4;++j) acc[i][j] = (f32x4){0.f,0.f,0.f,0.f};

  for (int kt = 0; kt < K; kt += 64) {
    #pragma unroll
    for (int it=0; it<4; ++it) {
      int idx = it*256 + tid;
      int row = idx >> 3, c8 = idx & 7;
      gll16(&A[(m0+row)*K + kt + c8*8], &As[(it*256 + wbase)*8]);
      gll16(&Bm[(n0+row)*K + kt + c8*8], &Bs[(it*256 + wbase)*8]);
    }
    __syncthreads();
    #pragma unroll
    for (int kk=0; kk<64; kk+=32) {
      bf16x8 af[4], bfr[4];
      #pragma unroll
      for (int i=0;i<4;++i) af[i] = *(const bf16x8*)&As[(wm*64 + i*16 + lr)*64 + kk + lk*8];
      #pragma unroll
      for (int j=0;j<4;++j) bfr[j] = *(const bf16x8*)&Bs[(wn*64 + j*16 + lr)*64 + kk + lk*8];
      #pragma unroll
      for (int i=0;i<4;++i)
        #pragma unroll
        for (int j=0;j<4;++j)
          acc[i][j] = __builtin_amdgcn_mfma_f32_16x16x32_bf16(af[i], bfr[j], acc[i][j], 0, 0, 0);
    }
    __syncthreads();
  }
  #pragma unroll
  for (int i=0;i<4;++i)
    #pragma unroll
    for (int j=0;j<4;++j)
      #pragma unroll
      for (int r=0;r<4;++r) {
        size_t row = m0 + wm*64 + i*16 + lk*4 + r;
        size_t col = n0 + wn*64 + j*16 + lr;
        Cm[row*N + col] = f2b(acc[i][j][r]);
      }
}

// ---------- column stats (sum, sumsq) with atomics; blockDim = C/8 ----------
__global__ void col_stats_v(const ushort* __restrict__ X, float* __restrict__ sums,
                            float* __restrict__ sqs, int C, int rpb)
{
  const int tid = threadIdx.x;
  const size_t r0 = (size_t)blockIdx.x * rpb;
  float s[8] = {0,0,0,0,0,0,0,0};
  float q[8] = {0,0,0,0,0,0,0,0};
  const ushort* base = X + r0*(size_t)C + (size_t)tid*8;
  for (int r=0;r<rpb;++r){
    uint4 u = *(const uint4*)(base + (size_t)r*C);
    const ushort* ub = (const ushort*)&u;
    #pragma unroll
    for (int e=0;e<8;++e){ float v=b2f(ub[e]); s[e]+=v; q[e]+=v*v; }
  }
  #pragma unroll
  for (int e=0;e<8;++e){
    atomicAdd(&sums[tid*8+e], s[e]);
    atomicAdd(&sqs [tid*8+e], q[e]);
  }
}

__global__ void bn_finalize(const float* __restrict__ sums, const float* __restrict__ sqs,
                            const float* __restrict__ g, const float* __restrict__ bb,
                            float* __restrict__ scale, float* __restrict__ shift, int C, float invn)
{
  int c = blockIdx.x*256 + threadIdx.x;
  if (c < C){
    float mu = sums[c]*invn;
    float var = sqs[c]*invn - mu*mu;
    float k = g[c] * rsqrtf(var + 1e-5f);
    scale[c] = k;
    shift[c] = bb[c] - mu*k;
  }
}

// ---------- BN + hardswish in place on y1 ----------
__global__ __launch_bounds__(256) void bn_hswish(ushort* __restrict__ y, const float* __restrict__ scale, const float* __restrict__ shift)
{
  __shared__ float sc[512], sh[512];
  for (int i=threadIdx.x;i<512;i+=256){ sc[i]=scale[i]; sh[i]=shift[i]; }
  __syncthreads();
  const size_t total = (size_t)73728*512/8;
  for (size_t idx = (size_t)blockIdx.x*256+threadIdx.x; idx < total; idx += (size_t)gridDim.x*256){
    uint4 u = *(uint4*)&y[idx*8];
    ushort* up = (ushort*)&u;
    int c0 = ((int)(idx & 63))*8;
    #pragma unroll
    for (int e=0;e<8;++e){
      float x = b2f(up[e])*sc[c0+e] + sh[c0+e];
      up[e] = f2b(hswish(x));
    }
    *(uint4*)&y[idx*8] = u;
  }
}

// ---------- q = text @ Wq^T (raw, f32) ----------
__global__ __launch_bounds__(256) void q_gemm(const float* __restrict__ text, const float* __restrict__ Wq, float* __restrict__ qraw)
{
  __shared__ __align__(16) float xr[512];
  const int t = blockIdx.x, tid = threadIdx.x;
  for (int i=tid;i<512;i+=256) xr[i] = text[t*512+i];
  __syncthreads();
  #pragma unroll
  for (int cj=0;cj<2;++cj){
    int c = cj*256+tid;
    const float4* wp = (const float4*)(Wq + (size_t)c*512);
    const float4* xp = (const float4*)xr;
    float a=0.f;
    for (int u=0;u<128;++u){
      float4 wv = wp[u], xv = xp[u];
      a += wv.x*xv.x + wv.y*xv.y + wv.z*xv.z + wv.w*xv.w;
    }
    qraw[t*512+c]=a;
  }
}

// ---------- q BN + fold K-BN scale into Qh (bf16), compute cQ[t,h] = 0.125*dot(q_bn, tk) ----------
__global__ __launch_bounds__(512) void q_bn_qh(const float* __restrict__ qraw, const float* __restrict__ g,
                                               const float* __restrict__ bb,
                                               const float* __restrict__ scale2, const float* __restrict__ shift2,
                                               ushort* __restrict__ Qh, float* __restrict__ cQ)
{
  const int c = threadIdx.x;
  const int h = c >> 6, d = c & 63;
  float s=0.f,q=0.f;
  for (int t=0;t<60;++t){ float v = qraw[t*512+c]; s+=v; q+=v*v; }
  float mu=s*(1.f/60.f), var=q*(1.f/60.f)-mu*mu;
  float k = g[c]*rsqrtf(var+1e-5f);
  float sh = bb[c]-mu*k;
  const float sk = scale2[h*192+d]*0.125f;
  const float tk = shift2[h*192+d]*0.125f;
  for (int t=0;t<60;++t){
    float qv = qraw[t*512+c]*k+sh;
    Qh[(h*64+t)*64+d] = f2b(qv*sk);
    float contrib = qv*tk;
    #pragma unroll
    for (int o=32;o>0;o>>=1) contrib += __shfl_xor(contrib,o);
    if (d==0) cQ[h*64+t] = contrib;
  }
  for (int t=60;t<64;++t) Qh[(h*64+t)*64+d] = 0;
}

// ---------- scores: S[bh][t][n] = Qh . Kraw + cQ + bias  (MFMA) ----------
__global__ __launch_bounds__(256) void scores_mfma(
    const ushort* __restrict__ Qh, const float* __restrict__ cQ,
    const ushort* __restrict__ kv, const float* __restrict__ biases,
    float* __restrict__ S)
{
  __shared__ __align__(16) ushort Qs[64*72];
  __shared__ float bias_l[10000];
  const int tid = threadIdx.x;
  const int l = tid & 63, w = tid >> 6;
  const int lr = l & 15, lk = l >> 4;
  const int h = blockIdx.y, b = blockIdx.z;
  const int n0 = blockIdx.x * 256;
  const int bh = b*8 + h;
  for (int cid = tid; cid < 512; cid += 256){
    int row = cid >> 3, c8 = cid & 7;
    *(uint4*)&Qs[row*72 + c8*8] = *(const uint4*)&Qh[(size_t)(h*64 + row)*64 + c8*8];
  }
  for (int i = tid; i < 10000; i += 256) bias_l[i] = biases[h*10000 + i];
  __syncthreads();
  f32x4 acc[4][4];
  #pragma unroll
  for (int i=0;i<4;++i)
    #pragma unroll
    for (int j=0;j<4;++j) acc[i][j]=(f32x4){0.f,0.f,0.f,0.f};
  const ushort* kbase = kv + ((size_t)(b*9216 + n0 + w*64))*1536 + h*192;
  #pragma unroll
  for (int kk=0; kk<64; kk+=32){
    bf16x8 af[4], bfr[4];
    #pragma unroll
    for (int i=0;i<4;++i) af[i] = *(const bf16x8*)&Qs[(i*16+lr)*72 + kk + lk*8];
    #pragma unroll
    for (int j=0;j<4;++j) bfr[j] = *(const bf16x8*)&kbase[(size_t)(j*16+lr)*1536 + kk + lk*8];
    #pragma unroll
    for (int i=0;i<4;++i)
      #pragma unroll
      for (int j=0;j<4;++j)
        acc[i][j] = __builtin_amdgcn_mfma_f32_16x16x32_bf16(af[i], bfr[j], acc[i][j], 0,0,0);
  }
  float* Sb = S + (size_t)bh*64*9216;
  #pragma unroll
  for (int j=0;j<4;++j){
    int n = n0 + w*64 + j*16 + lr;
    int py = n/96, px = n - py*96;
    const float* brow = &bias_l[100*py];
    #pragma unroll
    for (int i=0;i<4;++i){
      #pragma unroll
      for (int r=0;r<4;++r){
        int row = i*16 + lk*4 + r;
        if (row < 60){
          int dd = row - px; dd = dd<0?-dd:dd;
          Sb[(size_t)row*9216 + n] = acc[i][j][r] + cQ[h*64+row] + brow[dd];
        }
      }
    }
  }
}

// ---------- per-row softmax stats ----------
__global__ __launch_bounds__(256) void softmax_stats(const float* __restrict__ S, float* __restrict__ rmax_, float* __restrict__ rinv_)
{
  const int t = blockIdx.x, bh = blockIdx.y, tid = threadIdx.x;
  const float4* p = (const float4*)(S + ((size_t)bh*64 + t)*9216);
  float4 vals[9];
  float m = -1e30f;
  #pragma unroll
  for (int i=0;i<9;++i){ float4 v = p[i*256+tid]; vals[i]=v; m = fmaxf(m, fmaxf(fmaxf(v.x,v.y),fmaxf(v.z,v.w))); }
  #pragma unroll
  for (int o=32;o>0;o>>=1) m = fmaxf(m, __shfl_xor(m, o));
  __shared__ float wm[4], ws[4];
  if ((tid&63)==0) wm[tid>>6]=m;
  __syncthreads();
  m = fmaxf(fmaxf(wm[0],wm[1]),fmaxf(wm[2],wm[3]));
  float ssum=0.f;
  #pragma unroll
  for (int i=0;i<9;++i){ float4 v=vals[i]; ssum += __expf(v.x-m)+__expf(v.y-m)+__expf(v.z-m)+__expf(v.w-m); }
  #pragma unroll
  for (int o=32;o>0;o>>=1) ssum += __shfl_xor(ssum,o);
  if ((tid&63)==0) ws[tid>>6]=ssum;
  __syncthreads();
  if (tid==0){ rmax_[bh*64+t]=m; rinv_[bh*64+t]=1.f/(ws[0]+ws[1]+ws[2]+ws[3]); }
}

// ---------- PV: attn_o[b][t][h*128+dv] += P @ Vraw  (MFMA, V^T staged in LDS) ----------
__global__ __launch_bounds__(256) void pv_mfma(
    const float* __restrict__ S, const ushort* __restrict__ kv,
    const float* __restrict__ rmax_, const float* __restrict__ rinv_,
    float* __restrict__ attn_out)
{
  __shared__ ushort vt[128*68];
  const int tid = threadIdx.x;
  const int l = tid & 63, w = tid >> 6;
  const int lr = l & 15, lk = l >> 4;
  const int nc = blockIdx.x, h = blockIdx.y, b = blockIdx.z;
  const int bh = b*8+h;
  const size_t Sbase = (size_t)bh*64*9216;
  float rmv[4], riv[4];
  #pragma unroll
  for (int i=0;i<4;++i){ rmv[i]=rmax_[bh*64+i*16+lr]; riv[i]=rinv_[bh*64+i*16+lr]; }
  f32x4 acc[4][2];
  #pragma unroll
  for (int i=0;i<4;++i){ acc[i][0]=(f32x4){0.f,0.f,0.f,0.f}; acc[i][1]=(f32x4){0.f,0.f,0.f,0.f}; }
  for (int ks=0; ks<576; ks+=64){
    const int n0 = nc*576 + ks;
    if (ks) __syncthreads();
    #pragma unroll
    for (int c2=0;c2<4;++c2){
      int cid = c2*256 + tid;
      int row = cid >> 4, dv0 = (cid & 15)*8;
      uint4 vv = *(const uint4*)&kv[((size_t)(b*9216 + n0 + row))*1536 + h*192 + 64 + dv0];
      const ushort* vb8 = (const ushort*)&vv;
      #pragma unroll
      for (int e=0;e<8;++e) vt[(dv0+e)*68 + row] = vb8[e];
    }
    __syncthreads();
    #pragma unroll
    for (int kk=0; kk<64; kk+=32){
      bf16x8 pa[4], vb[2];
      #pragma unroll
      for (int i=0;i<4;++i){
        const float* sp = S + Sbase + (size_t)(i*16+lr)*9216 + n0 + kk + lk*8;
        float4 s0 = *(const float4*)sp, s1 = *(const float4*)(sp+4);
        float rm=rmv[i], ri=riv[i];
        bf16x8 t_;
        t_[0]=(short)f2b(__expf(s0.x-rm)*ri);
        t_[1]=(short)f2b(__expf(s0.y-rm)*ri);
        t_[2]=(short)f2b(__expf(s0.z-rm)*ri);
        t_[3]=(short)f2b(__expf(s0.w-rm)*ri);
        t_[4]=(short)f2b(__expf(s1.x-rm)*ri);
        t_[5]=(short)f2b(__expf(s1.y-rm)*ri);
        t_[6]=(short)f2b(__expf(s1.z-rm)*ri);
        t_[7]=(short)f2b(__expf(s1.w-rm)*ri);
        pa[i]=t_;
      }
      #pragma unroll
      for (int j=0;j<2;++j){
        const ushort* vp = &vt[(w*32 + j*16 + lr)*68 + kk + lk*8];
        uint2 a0 = *(const uint2*)vp, a1 = *(const uint2*)(vp+4);
        struct PP { uint2 a,b; } pp{a0,a1};
        vb[j] = __builtin_bit_cast(bf16x8, pp);
      }
      #pragma unroll
      for (int i=0;i<4;++i){
        acc[i][0] = __builtin_amdgcn_mfma_f32_16x16x32_bf16(pa[i], vb[0], acc[i][0],0,0,0);
        acc[i][1] = __builtin_amdgcn_mfma_f32_16x16x32_bf16(pa[i], vb[1], acc[i][1],0,0,0);
      }
    }
  }
  float* ob = attn_out + (size_t)(b*60)*1024 + h*128;
  #pragma unroll
  for (int j=0;j<2;++j){
    int dv = w*32 + j*16 + lr;
    #pragma unroll
    for (int i=0;i<4;++i)
      #pragma unroll
      for (int r=0;r<4;++r){
        int row = i*16 + lk*4 + r;
        if (row < 60) atomicAdd(&ob[(size_t)row*1024 + dv], acc[i][j][r]);
      }
  }
}

// ---------- row GEMM, 8 rows/block. MODE 0: id; 2: BN direct; 3: attn-BN map. hswish if MODE>=1 ----------
template<int CIN, int COUT, int MODE>
__global__ __launch_bounds__(256) void rowgemm8(
    const float* __restrict__ X, const float* __restrict__ Wt,
    const float* __restrict__ sc, const float* __restrict__ sh,
    float* __restrict__ out)
{
  __shared__ __align__(16) float xr[8][CIN];
  const int rb0 = blockIdx.x*8, tid = threadIdx.x;
  for (int i=tid; i<8*CIN; i+=256){
    int rr = i / CIN, cc = i % CIN;
    float v = X[(size_t)(rb0+rr)*CIN + cc];
    if constexpr (MODE==2) v = v*sc[cc]+sh[cc];
    if constexpr (MODE==3){ int idx = 64 + (cc&127) + (cc>>7)*192; v = v*sc[idx]+sh[idx]; }
    if constexpr (MODE>=1) v = hswish(v);
    xr[rr][cc]=v;
  }
  __syncthreads();
  #pragma unroll
  for (int cj=0; cj<COUT/256; ++cj){
    int c = cj*256 + tid;
    const float4* wp = (const float4*)(Wt + (size_t)c*CIN);
    float a[8] = {0.f,0.f,0.f,0.f,0.f,0.f,0.f,0.f};
    for (int u=0;u<CIN/4;++u){
      float4 wv = wp[u];
      #pragma unroll
      for (int rr=0;rr<8;++rr){
        float4 xv = *(const float4*)&xr[rr][u*4];
        a[rr] += wv.x*xv.x + wv.y*xv.y + wv.z*xv.z + wv.w*xv.w;
      }
    }
    #pragma unroll
    for (int rr=0;rr<8;++rr) out[(size_t)(rb0+rr)*COUT + c] = a[rr];
  }
}

template<int C>
__global__ void stats480(const float* __restrict__ X, const float* __restrict__ g,
                         const float* __restrict__ bb, float* __restrict__ sc, float* __restrict__ sh)
{
  int c = blockIdx.x*256 + threadIdx.x;
  float s=0.f, q=0.f;
  for (int r=0;r<480;++r){ float v = X[(size_t)r*C + c]; s+=v; q+=v*v; }
  float mu = s*(1.f/480.f), var = q*(1.f/480.f)-mu*mu;
  float k = g[c] * rsqrtf(var+1e-5f);
  sc[c]=k; sh[c]=bb[c] - mu*k;
}

__global__ void make_textd(const float* __restrict__ praw, const float* __restrict__ sp, const float* __restrict__ tp,
                           const float* __restrict__ text, float* __restrict__ textd)
{
  int i = blockIdx.x*256+threadIdx.x;
  if (i < 480*512){
    int c = i & 511, rb = i >> 9, t = rb % 60;
    textd[i] = text[t*512+c] + praw[i]*sp[c]+tp[c];
  }
}

__global__ void final_out(const float* __restrict__ f2raw, const float* __restrict__ sf, const float* __restrict__ tf,
                          const float* __restrict__ textd, float* __restrict__ outp)
{
  int i = blockIdx.x*256+threadIdx.x;
  if (i < 60*512){ int c = i & 511; outp[i] = f2raw[i]*sf[c]+tf[c] + textd[i]; }
}

extern "C" void kernel_launch(void* const* d_in, const int* in_sizes, int n_in,
                              void* d_out, int out_size, void* d_ws, size_t ws_size,
                              hipStream_t stream)
{
  (void)in_sizes; (void)n_in; (void)out_size; (void)ws_size;
  const float* im    = (const float*)d_in[0];
  const float* text  = (const float*)d_in[1];
  const float* W_dc  = (const float*)d_in[2];
  const float* g_dc  = (const float*)d_in[3];
  const float* b_dc  = (const float*)d_in[4];
  const float* W_kv  = (const float*)d_in[5];
  const float* g_kv  = (const float*)d_in[6];
  const float* b_kv  = (const float*)d_in[7];
  const float* W_q   = (const float*)d_in[8];
  const float* g_q   = (const float*)d_in[9];
  const float* b_q   = (const float*)d_in[10];
  const float* W_proj= (const float*)d_in[11];
  const float* g_proj= (const float*)d_in[12];
  const float* b_proj= (const float*)d_in[13];
  const float* biases= (const float*)d_in[14];
  const float* W_f1  = (const float*)d_in[15];
  const float* g_f1  = (const float*)d_in[16];
  const float* b_f1  = (const float*)d_in[17];
  const float* W_f2  = (const float*)d_in[18];
  const float* g_f2  = (const float*)d_in[19];
  const float* b_f2  = (const float*)d_in[20];
  float* outp = (float*)d_out;

  char* p = (char*)d_ws;
  auto alloc = [&](size_t bytes)->char*{ char* r = p; p += (bytes+255)&~(size_t)255; return r; };
  // zero zone (contiguous)
  float* s1_sum = (float*)alloc(512*4);
  float* s1_sq  = (float*)alloc(512*4);
  float* s2_sum = (float*)alloc(1536*4);
  float* s2_sq  = (float*)alloc(1536*4);
  float* attn_o = (float*)alloc((size_t)480*1024*4);
  float* zero_base = s1_sum; const int zero_n = 495616;
  // rest
  float* sc1 = (float*)alloc(512*4);
  float* sh1 = (float*)alloc(512*4);
  float* sc2 = (float*)alloc(1536*4);
  float* sh2 = (float*)alloc(1536*4);
  float* qraw = (float*)alloc(60*512*4);
  ushort* Qh = (ushort*)alloc((size_t)8*64*64*2);
  float* cQ = (float*)alloc(512*4);
  float* rmaxb = (float*)alloc(4096*4);
  float* rinvb = (float*)alloc(4096*4);
  float* proj_raw = (float*)alloc((size_t)480*512*4);
  float* sp=(float*)alloc(512*4); float* tp=(float*)alloc(512*4);
  float* textd=(float*)alloc((size_t)480*512*4);
  float* sf1=(float*)alloc(1024*4); float* tf1=(float*)alloc(1024*4);
  float* f1_raw=(float*)alloc((size_t)480*1024*4);
  float* sf2=(float*)alloc(512*4); float* tf2=(float*)alloc(512*4);
  float* f2_raw=(float*)alloc((size_t)480*512*4);
  ushort* Wdc_b = (ushort*)alloc((size_t)512*1024*2);
  ushort* Wkv_b = (ushort*)alloc((size_t)1536*512*2);
  ushort* y1 = (ushort*)alloc((size_t)73728*512*2);
  ushort* kv = (ushort*)alloc((size_t)73728*1536*2);
  ushort* At = (ushort*)alloc((size_t)73728*1024*2);
  float* S = (float*)At;  // alias: At dead after gemm1; S[64bh][64][9216] f32 == At bytes exactly

  zero_f32<<<1936,256,0,stream>>>(zero_base, zero_n);
  cvt_bf16<<<2048,256,0,stream>>>(W_dc, Wdc_b, 512*1024);
  cvt_bf16<<<3072,256,0,stream>>>(W_kv, Wkv_b, 1536*512);
  transpose_kernel<<<dim3(144,16,8),256,0,stream>>>(im, At);
  gemm_bt<<<dim3(576,4),256,0,stream>>>(At, Wdc_b, y1, 73728, 512, 1024);
  col_stats_v<<<288,64,0,stream>>>(y1, s1_sum, s1_sq, 512, 256);
  bn_finalize<<<2,256,0,stream>>>(s1_sum, s1_sq, g_dc, b_dc, sc1, sh1, 512, 1.f/73728.f);
  bn_hswish<<<2048,256,0,stream>>>(y1, sc1, sh1);
  gemm_bt<<<dim3(576,12),256,0,stream>>>(y1, Wkv_b, kv, 73728, 1536, 512);
  col_stats_v<<<288,192,0,stream>>>(kv, s2_sum, s2_sq, 1536, 256);
  bn_finalize<<<6,256,0,stream>>>(s2_sum, s2_sq, g_kv, b_kv, sc2, sh2, 1536, 1.f/73728.f);
  q_gemm<<<60,256,0,stream>>>(text, W_q, qraw);
  q_bn_qh<<<1,512,0,stream>>>(qraw, g_q, b_q, sc2, sh2, Qh, cQ);
  scores_mfma<<<dim3(36,8,8),256,0,stream>>>(Qh, cQ, kv, biases, S);
  softmax_stats<<<dim3(60,64),256,0,stream>>>(S, rmaxb, rinvb);
  pv_mfma<<<dim3(16,8,8),256,0,stream>>>(S, kv, rmaxb, rinvb, attn_o);
  rowgemm8<1024,512,3><<<60,256,0,stream>>>(attn_o, W_proj, sc2, sh2, proj_raw);
  stats480<512><<<2,256,0,stream>>>(proj_raw, g_proj, b_proj, sp, tp);
  make_textd<<<960,256,0,stream>>>(proj_raw, sp, tp, text, textd);
  rowgemm8<512,1024,0><<<60,256,0,stream>>>(textd, W_f1, nullptr, nullptr, f1_raw);
  stats480<1024><<<4,256,0,stream>>>(f1_raw, g_f1, b_f1, sf1, tf1);
  rowgemm8<1024,512,2><<<60,256,0,stream>>>(f1_raw, W_f2, sf1, tf1, f2_raw);
  stats480<512><<<2,256,0,stream>>>(f2_raw, g_f2, b_f2, sf2, tf2);
  final_out<<<120,256,0,stream>>>(f2_raw, sf2, tf2, textd, outp);
}